// Round 3
// baseline (255.839 us; speedup 1.0000x reference)
//
#include <hip/hip_runtime.h>
#include <hip/hip_fp16.h>

#define N_NODES 50000
#define N_EDGES 800000
#define E_TOT   850000           // edges + self loops
#define IN_DIM  128
#define HID     64
#define HEADS   4
#define C1      256              // HEADS*HID
#define OUT_DIM 64
#define NEG_SLOPE 0.2f

#define CP_NODES   32                              // nodes per proj block
#define CP_BLOCKS  ((N_NODES + CP_NODES - 1) / CP_NODES)   // 1563
#define COUNT_BLOCKS ((E_TOT + 255) / 256)         // 3321
#define NB_SCAN ((N_NODES + 255) / 256)            // 196

typedef __attribute__((ext_vector_type(8))) short v8s;   // 8 bf16 (4 VGPRs)
typedef __attribute__((ext_vector_type(4))) float v4f;   // MFMA accumulator

// ---- bf16 helpers (manual: bf16 = top 16 bits of fp32, RNE) ----------------
__device__ __forceinline__ unsigned int bf16_rne(float f) {
    unsigned int u = __float_as_uint(f);
    return (u + 0x7FFFu + ((u >> 16) & 1u)) >> 16;
}
__device__ __forceinline__ unsigned int bf16_pack2(float a, float b) {
    return bf16_rne(a) | (bf16_rne(b) << 16);
}
__device__ __forceinline__ float bf16_lo(unsigned int u) { return __uint_as_float(u << 16); }
__device__ __forceinline__ float bf16_hi(unsigned int u) { return __uint_as_float(u & 0xFFFF0000u); }

// ---- fp16 pack helpers for edge weights ------------------------------------
__device__ __forceinline__ unsigned int f16_pack2(float a, float b) {
    __half2 h = __floats2half2_rn(a, b);
    return *(unsigned int*)&h;
}
__device__ __forceinline__ float2 f16_unp2(unsigned int u) {
    __half2 h = *(__half2*)&u;
    return __half22float2(h);
}

// ---------------------------------------------------------------------------
// prep: p_src/p_dst collapse the layer-1 logit projection; v_s/v_d/v_z
// collapse ALL consumers of h2; cst = b2.fc_w + fc_b; W1 -> bf16 B-fragments.
// ---------------------------------------------------------------------------
__global__ __launch_bounds__(512) void prep_kernel(
    const float* __restrict__ W1, const float* __restrict__ a_src1,
    const float* __restrict__ a_dst1,
    const float* __restrict__ W2, const float* __restrict__ a_src2,
    const float* __restrict__ a_dst2, const float* __restrict__ b2,
    const float* __restrict__ fc_w, const float* __restrict__ fc_b,
    float* __restrict__ p_src, float* __restrict__ p_dst,
    float* __restrict__ v_s, float* __restrict__ v_d, float* __restrict__ v_z,
    float* __restrict__ cst, unsigned int* __restrict__ W1b)
{
    const int t = threadIdx.x;                 // 512 = 128 k * 4 h
    const int k = t >> 2, h = t & 3;
    const float* wrow = W1 + k * C1 + h * HID;
    const float* as = a_src1 + h * HID;
    const float* ad = a_dst1 + h * HID;
    float s = 0.f, d = 0.f;
    for (int c = 0; c < HID; c++) {
        float w = wrow[c];
        s = fmaf(w, as[c], s);
        d = fmaf(w, ad[c], d);
    }
    p_src[k * HEADS + h] = s;
    p_dst[k * HEADS + h] = d;

    if (t < C1) {                              // layer-2 collapse vectors
        const float* w2row = W2 + t * OUT_DIM;
        float vs = 0.f, vd = 0.f, vz = 0.f;
        for (int c = 0; c < OUT_DIM; c++) {
            float w = w2row[c];
            vs = fmaf(w, a_src2[c], vs);
            vd = fmaf(w, a_dst2[c], vd);
            vz = fmaf(w, fc_w[c], vz);
        }
        v_s[t] = vs; v_d[t] = vd; v_z[t] = vz;
    }
    if (t == 0) {
        float s2 = 0.f;
        for (int c = 0; c < OUT_DIM; c++) s2 = fmaf(b2[c], fc_w[c], s2);
        cst[0] = s2 + fc_b[0];
    }

    // W1 -> bf16 B-fragment packing (16384 uints = 64 KB)
    for (int idx = t; idx < 16384; idx += 512) {
        int i    = idx & 3;
        int lane = (idx >> 2) & 63;
        int kk   = (idx >> 8) & 3;
        int nt   = (idx >> 10) & 3;
        int hh   = idx >> 12;
        int k0 = kk * 32 + (lane >> 4) * 8 + i * 2;
        int c  = hh * 64 + nt * 16 + (lane & 15);
        W1b[idx] = bf16_pack2(W1[(size_t)k0 * C1 + c], W1[(size_t)(k0 + 1) * C1 + c]);
    }
}

// ---------------------------------------------------------------------------
// convproj_count: fused launch (round-17 proven mapping).
// ---------------------------------------------------------------------------
__global__ __launch_bounds__(256) void convproj_count_kernel(
    const float* __restrict__ x, const float* __restrict__ p_src,
    const float* __restrict__ p_dst, const int* __restrict__ dst_a,
    float* __restrict__ as1, float* __restrict__ ad1,
    unsigned int* __restrict__ xb, int* __restrict__ deg,
    int* __restrict__ posE)
{
    if (blockIdx.x >= CP_BLOCKS) {             // ---- count part ----
        int j = (blockIdx.x - CP_BLOCKS) * 256 + threadIdx.x;
        if (j < E_TOT) {
            int d = (j < N_EDGES) ? dst_a[j] : (j - N_EDGES);   // self loop
            posE[j] = atomicAdd(&deg[d], 1);
        }
        return;
    }
    // ---- proj + convert part ----
    __shared__ float ps[IN_DIM * HEADS];       // 2 KB
    __shared__ float pd[IN_DIM * HEADS];       // 2 KB
    const int t = threadIdx.x;
    for (int i = t; i < IN_DIM * HEADS; i += 256) { ps[i] = p_src[i]; pd[i] = p_dst[i]; }
    __syncthreads();
    const int wv   = t >> 6;
    const int lane = t & 63;
    float4 p0 = *(const float4*)(ps + (lane * 2) * HEADS);
    float4 p1 = *(const float4*)(ps + (lane * 2 + 1) * HEADS);
    float4 q0 = *(const float4*)(pd + (lane * 2) * HEADS);
    float4 q1 = *(const float4*)(pd + (lane * 2 + 1) * HEADS);
    const int nodeBase = blockIdx.x * CP_NODES + wv * 8;   // wave: 8 contiguous nodes
    #pragma unroll
    for (int i = 0; i < 8; i++) {
        const int node = nodeBase + i;
        if (node >= N_NODES) break;
        float2 xv = *(const float2*)(x + (size_t)node * IN_DIM + lane * 2);
        xb[(size_t)node * 64 + lane] = bf16_pack2(xv.x, xv.y);
        float s0 = xv.x * p0.x + xv.y * p1.x;
        float s1 = xv.x * p0.y + xv.y * p1.y;
        float s2 = xv.x * p0.z + xv.y * p1.z;
        float s3 = xv.x * p0.w + xv.y * p1.w;
        float d0 = xv.x * q0.x + xv.y * q1.x;
        float d1 = xv.x * q0.y + xv.y * q1.y;
        float d2 = xv.x * q0.z + xv.y * q1.z;
        float d3 = xv.x * q0.w + xv.y * q1.w;
        #pragma unroll
        for (int off = 32; off; off >>= 1) {
            s0 += __shfl_down(s0, off, 64); s1 += __shfl_down(s1, off, 64);
            s2 += __shfl_down(s2, off, 64); s3 += __shfl_down(s3, off, 64);
            d0 += __shfl_down(d0, off, 64); d1 += __shfl_down(d1, off, 64);
            d2 += __shfl_down(d2, off, 64); d3 += __shfl_down(d3, off, 64);
        }
        if (lane == 0) {
            float4 sv = {s0, s1, s2, s3};
            float4 dv = {d0, d1, d2, d3};
            *(float4*)(as1 + node * 4) = sv;
            *(float4*)(ad1 + node * 4) = dv;
        }
    }
}

// ---------------------------------------------------------------------------
// Parallel CSR scan: blocksum -> scanbsum -> expand
// ---------------------------------------------------------------------------
__global__ __launch_bounds__(256) void blocksum_kernel(
    const int* __restrict__ deg, int* __restrict__ bsum)
{
    __shared__ int ps[256];
    const int t = threadIdx.x;
    int i = blockIdx.x * 256 + t;
    ps[t] = (i < N_NODES) ? deg[i] : 0;
    __syncthreads();
    for (int off = 128; off; off >>= 1) {
        if (t < off) ps[t] += ps[t + off];
        __syncthreads();
    }
    if (t == 0) bsum[blockIdx.x] = ps[0];
}

__global__ __launch_bounds__(256) void scanbsum_kernel(
    const int* __restrict__ bsum, int* __restrict__ boff)
{
    __shared__ int ps[256];
    const int t = threadIdx.x;
    ps[t] = (t < NB_SCAN) ? bsum[t] : 0;
    __syncthreads();
    for (int off = 1; off < 256; off <<= 1) {
        int u = (t >= off) ? ps[t - off] : 0;
        __syncthreads();
        ps[t] += u;
        __syncthreads();
    }
    boff[t] = (t > 0) ? ps[t - 1] : 0;         // exclusive
}

__global__ __launch_bounds__(256) void expand_kernel(
    const int* __restrict__ deg, const int* __restrict__ boff,
    int* __restrict__ rowptr)
{
    __shared__ int ps[256];
    const int t = threadIdx.x;
    int i = blockIdx.x * 256 + t;
    int v = (i < N_NODES) ? deg[i] : 0;
    ps[t] = v;
    __syncthreads();
    for (int off = 1; off < 256; off <<= 1) {
        int u = (t >= off) ? ps[t - off] : 0;
        __syncthreads();
        ps[t] += u;
        __syncthreads();
    }
    if (i <= N_NODES) rowptr[i] = boff[blockIdx.x] + ps[t] - v;   // exclusive
}

// ---------------------------------------------------------------------------
// fillw3: atomic-free CSR fill with ONE 16 B sorted record per edge:
// rec[slot] = {src, w01(2xf16), w23(2xf16), 0}.
// ---------------------------------------------------------------------------
__global__ void fillw3_kernel(const int* __restrict__ src_a, const int* __restrict__ dst_a,
                              const int* __restrict__ rowptr, const int* __restrict__ posE,
                              const float* __restrict__ as1, const float* __restrict__ ad1,
                              int4* __restrict__ rec)
{
    int j = blockIdx.x * blockDim.x + threadIdx.x;
    if (j >= E_TOT) return;
    int s, d;
    if (j < N_EDGES) { s = src_a[j]; d = dst_a[j]; }
    else             { s = j - N_EDGES; d = s; }
    int slot = rowptr[d] + posE[j];
    float4 A  = *(const float4*)(as1 + s * 4);
    float4 Dv = *(const float4*)(ad1 + d * 4);
    float a0 = A.x + Dv.x, a1 = A.y + Dv.y, a2 = A.z + Dv.z, a3 = A.w + Dv.w;
    a0 = a0 > 0.f ? a0 : NEG_SLOPE * a0;
    a1 = a1 > 0.f ? a1 : NEG_SLOPE * a1;
    a2 = a2 > 0.f ? a2 : NEG_SLOPE * a2;
    a3 = a3 > 0.f ? a3 : NEG_SLOPE * a3;
    int4 r;
    r.x = s;
    r.y = (int)f16_pack2(__expf(a0), __expf(a1));
    r.z = (int)f16_pack2(__expf(a2), __expf(a3));
    r.w = 0;
    rec[slot] = r;                             // single 16 B scatter
}

// ---------------------------------------------------------------------------
// agg1mlp: FUSED agg1x + mlp (v2).
//  8 waves/block (512 thr), 2 nodes/wave: 25000 total waves -> 3.05 occupancy
//  rounds (was 1.53 -> 55% occ), finer intra-block balance.
//  Phase A inner loop software-pipelined: next 4 rec records prefetched
//  before the FMA block so rec-latency hides under gather-wait + FMA.
//  Phase B: wave w -> head (w>>1), nt-pair (w&1); cross-wave reduce over 8.
// ---------------------------------------------------------------------------
__global__ __launch_bounds__(512, 8) void agg1mlp_kernel(
    const int* __restrict__ rowptr, const int4* __restrict__ rec,
    const unsigned int* __restrict__ xb,
    const unsigned int* __restrict__ W1b, const float* __restrict__ b1,
    const float* __restrict__ v_s, const float* __restrict__ v_d,
    const float* __restrict__ v_z,
    float2* __restrict__ az, float* __restrict__ ad2)
{
    __shared__ unsigned int xsh[16 * 260];     // 16.6 KB bf16 tile (+pad)
    __shared__ float pr[8 * 16 * 3];           // 1.5 KB cross-wave partials
    const int t = threadIdx.x;
    const int nodeBase = blockIdx.x * 16;      // 3125 blocks * 16 = 50000 exact
    const int wv   = t >> 6;                   // 0..7
    const int lane = t & 63;

    // ---- Phase A: aggregate 2 nodes per wave, straight into LDS ----
    #pragma unroll 1
    for (int i = 0; i < 2; i++) {
        const int ln = wv * 2 + i;             // local node 0..15
        const int n  = nodeBase + ln;
        const int e0 = rowptr[n], e1 = rowptr[n + 1];

        float2 acc0 = {0,0}, acc1 = {0,0}, acc2 = {0,0}, acc3 = {0,0};
        float den0 = 0, den1 = 0, den2 = 0, den3 = 0;
        int e = e0;
        int4 R0, R1, R2, R3;
        if (e + 4 <= e1) {                     // pipeline prologue
            R0 = rec[e]; R1 = rec[e + 1]; R2 = rec[e + 2]; R3 = rec[e + 3];
        }
        while (e + 4 <= e1) {
            // issue the 4 gathers that depend on current records
            unsigned int xu0 = xb[(size_t)R0.x * 64 + lane];
            unsigned int xu1 = xb[(size_t)R1.x * 64 + lane];
            unsigned int xu2 = xb[(size_t)R2.x * 64 + lane];
            unsigned int xu3 = xb[(size_t)R3.x * 64 + lane];
            // keep weights in regs, then prefetch NEXT records (independent
            // of the gathers above -> stays in flight across the FMA block)
            unsigned int wy0 = R0.y, wz0 = R0.z, wy1 = R1.y, wz1 = R1.z;
            unsigned int wy2 = R2.y, wz2 = R2.z, wy3 = R3.y, wz3 = R3.z;
            e += 4;
            if (e + 4 <= e1) {
                R0 = rec[e]; R1 = rec[e + 1]; R2 = rec[e + 2]; R3 = rec[e + 3];
            }
            float2 W0a = f16_unp2(wy0), W0b = f16_unp2(wz0);
            float2 W1a = f16_unp2(wy1), W1b_ = f16_unp2(wz1);
            float2 W2a = f16_unp2(wy2), W2b = f16_unp2(wz2);
            float2 W3a = f16_unp2(wy3), W3b = f16_unp2(wz3);
            float a0 = bf16_lo(xu0), b0 = bf16_hi(xu0);
            float a1 = bf16_lo(xu1), b1v = bf16_hi(xu1);
            float a2 = bf16_lo(xu2), b2v = bf16_hi(xu2);
            float a3 = bf16_lo(xu3), b3v = bf16_hi(xu3);
            acc0.x = fmaf(W0a.x, a0, acc0.x); acc0.y = fmaf(W0a.x, b0, acc0.y);
            acc1.x = fmaf(W0a.y, a0, acc1.x); acc1.y = fmaf(W0a.y, b0, acc1.y);
            acc2.x = fmaf(W0b.x, a0, acc2.x); acc2.y = fmaf(W0b.x, b0, acc2.y);
            acc3.x = fmaf(W0b.y, a0, acc3.x); acc3.y = fmaf(W0b.y, b0, acc3.y);
            acc0.x = fmaf(W1a.x, a1, acc0.x); acc0.y = fmaf(W1a.x, b1v, acc0.y);
            acc1.x = fmaf(W1a.y, a1, acc1.x); acc1.y = fmaf(W1a.y, b1v, acc1.y);
            acc2.x = fmaf(W1b_.x, a1, acc2.x); acc2.y = fmaf(W1b_.x, b1v, acc2.y);
            acc3.x = fmaf(W1b_.y, a1, acc3.x); acc3.y = fmaf(W1b_.y, b1v, acc3.y);
            acc0.x = fmaf(W2a.x, a2, acc0.x); acc0.y = fmaf(W2a.x, b2v, acc0.y);
            acc1.x = fmaf(W2a.y, a2, acc1.x); acc1.y = fmaf(W2a.y, b2v, acc1.y);
            acc2.x = fmaf(W2b.x, a2, acc2.x); acc2.y = fmaf(W2b.x, b2v, acc2.y);
            acc3.x = fmaf(W2b.y, a2, acc3.x); acc3.y = fmaf(W2b.y, b2v, acc3.y);
            acc0.x = fmaf(W3a.x, a3, acc0.x); acc0.y = fmaf(W3a.x, b3v, acc0.y);
            acc1.x = fmaf(W3a.y, a3, acc1.x); acc1.y = fmaf(W3a.y, b3v, acc1.y);
            acc2.x = fmaf(W3b.x, a3, acc2.x); acc2.y = fmaf(W3b.x, b3v, acc2.y);
            acc3.x = fmaf(W3b.y, a3, acc3.x); acc3.y = fmaf(W3b.y, b3v, acc3.y);
            den0 += (W0a.x + W1a.x) + (W2a.x + W3a.x);
            den1 += (W0a.y + W1a.y) + (W2a.y + W3a.y);
            den2 += (W0b.x + W1b_.x) + (W2b.x + W3b.x);
            den3 += (W0b.y + W1b_.y) + (W2b.y + W3b.y);
        }
        for (; e < e1; e++) {                  // 0..3 remainder edges
            int4 r0 = rec[e];
            unsigned int xu = xb[(size_t)r0.x * 64 + lane];
            float2 Wa = f16_unp2(r0.y), Wb = f16_unp2(r0.z);
            float xa = bf16_lo(xu), xbv = bf16_hi(xu);
            acc0.x = fmaf(Wa.x, xa, acc0.x); acc0.y = fmaf(Wa.x, xbv, acc0.y);
            acc1.x = fmaf(Wa.y, xa, acc1.x); acc1.y = fmaf(Wa.y, xbv, acc1.y);
            acc2.x = fmaf(Wb.x, xa, acc2.x); acc2.y = fmaf(Wb.x, xbv, acc2.y);
            acc3.x = fmaf(Wb.y, xa, acc3.x); acc3.y = fmaf(Wb.y, xbv, acc3.y);
            den0 += Wa.x; den1 += Wa.y; den2 += Wb.x; den3 += Wb.y;
        }
        float i0 = 1.f / (den0 + 1e-16f), i1 = 1.f / (den1 + 1e-16f);
        float i2 = 1.f / (den2 + 1e-16f), i3 = 1.f / (den3 + 1e-16f);
        unsigned int* o = xsh + ln * 260 + lane;   // c = h*64 + lane
        o[0 * 64] = bf16_pack2(acc0.x * i0, acc0.y * i0);
        o[1 * 64] = bf16_pack2(acc1.x * i1, acc1.y * i1);
        o[2 * 64] = bf16_pack2(acc2.x * i2, acc2.y * i2);
        o[3 * 64] = bf16_pack2(acc3.x * i3, acc3.y * i3);
    }
    __syncthreads();

    {   // ---- Phase B: MFMA + register epilogue; wave w = (head, nt-pair) ----
        const int h = wv >> 1;                 // head 0..3
        const int ntb = (wv & 1) * 2;          // nt base: 0 or 2
        const int m = lane & 15, quad = lane >> 4;
        const unsigned int* abase = xsh + m * 260 + h * 64 + quad * 4;
        v8s af0 = *(const v8s*)(abase + 0);
        v8s af1 = *(const v8s*)(abase + 16);
        v8s af2 = *(const v8s*)(abase + 32);
        v8s af3 = *(const v8s*)(abase + 48);

        float Sr[4] = {0,0,0,0}, Dr[4] = {0,0,0,0}, Zr[4] = {0,0,0,0};
        #pragma unroll
        for (int j = 0; j < 2; j++) {
            const int nt = ntb + j;
            const unsigned int* bbase = W1b + (size_t)(h * 16 + nt * 4) * 256 + lane * 4;
            v4f acc = {0.f, 0.f, 0.f, 0.f};
            acc = __builtin_amdgcn_mfma_f32_16x16x32_bf16(af0, *(const v8s*)(bbase + 0 * 256), acc, 0, 0, 0);
            acc = __builtin_amdgcn_mfma_f32_16x16x32_bf16(af1, *(const v8s*)(bbase + 1 * 256), acc, 0, 0, 0);
            acc = __builtin_amdgcn_mfma_f32_16x16x32_bf16(af2, *(const v8s*)(bbase + 2 * 256), acc, 0, 0, 0);
            acc = __builtin_amdgcn_mfma_f32_16x16x32_bf16(af3, *(const v8s*)(bbase + 3 * 256), acc, 0, 0, 0);
            const int c = h * 64 + nt * 16 + m;
            float bb = b1[c], vsc = v_s[c], vdc = v_d[c], vzc = v_z[c];
            #pragma unroll
            for (int r = 0; r < 4; r++) {
                float o = acc[r] + bb;
                o = o > 0.f ? o : __expf(o) - 1.f;     // ELU
                Sr[r] = fmaf(o, vsc, Sr[r]);
                Dr[r] = fmaf(o, vdc, Dr[r]);
                Zr[r] = fmaf(o, vzc, Zr[r]);
            }
        }
        #pragma unroll
        for (int off = 8; off; off >>= 1) {            // reduce over 16 cols
            #pragma unroll
            for (int r = 0; r < 4; r++) {
                Sr[r] += __shfl_down(Sr[r], off, 16);
                Dr[r] += __shfl_down(Dr[r], off, 16);
                Zr[r] += __shfl_down(Zr[r], off, 16);
            }
        }
        if (m == 0) {
            #pragma unroll
            for (int r = 0; r < 4; r++) {
                const int row = quad * 4 + r;          // local node 0..15
                pr[(wv * 16 + row) * 3 + 0] = Sr[r];
                pr[(wv * 16 + row) * 3 + 1] = Dr[r];
                pr[(wv * 16 + row) * 3 + 2] = Zr[r];
            }
        }
    }
    __syncthreads();

    if (t < 16) {   // ---- cross-wave reduce + store ----
        float s = 0.f, d = 0.f, z = 0.f;
        #pragma unroll
        for (int w = 0; w < 8; w++) {
            s += pr[(w * 16 + t) * 3 + 0];
            d += pr[(w * 16 + t) * 3 + 1];
            z += pr[(w * 16 + t) * 3 + 2];
        }
        const int node = nodeBase + t;
        float2 azv = {s, z};
        az[node]  = azv;
        ad2[node] = d;
    }
}

// ---------------------------------------------------------------------------
// agg2z: out[n] = sum_e w_e * z[src] / sum_e w_e + cst.  Reads rec[e].x.
// ---------------------------------------------------------------------------
__global__ __launch_bounds__(256) void agg2z_kernel(
    const int* __restrict__ rowptr, const int4* __restrict__ rec,
    const float2* __restrict__ az, const float* __restrict__ ad2,
    const float* __restrict__ cst, float* __restrict__ out)
{
    int gid  = blockIdx.x * blockDim.x + threadIdx.x;
    int n    = gid >> 3;                       // 8 lanes per node
    int sl   = threadIdx.x & 7;
    if (n >= N_NODES) return;
    const float adh = ad2[n];
    const int e0 = rowptr[n], e1 = rowptr[n + 1];

    float acc = 0.f, den = 0.f;
    for (int e = e0 + sl; e < e1; e += 8) {
        int s = rec[e].x;
        float2 v = az[s];
        float a = v.x + adh;
        a = a > 0.f ? a : NEG_SLOPE * a;
        float w = __expf(a);
        acc = fmaf(w, v.y, acc);
        den += w;
    }
    #pragma unroll
    for (int off = 4; off; off >>= 1) {
        acc += __shfl_down(acc, off, 8);
        den += __shfl_down(den, off, 8);
    }
    if (sl == 0) out[n] = acc / (den + 1e-16f) + cst[0];
}

extern "C" void kernel_launch(void* const* d_in, const int* in_sizes, int n_in,
                              void* d_out, int out_size, void* d_ws, size_t ws_size,
                              hipStream_t stream)
{
    const float* x      = (const float*)d_in[0];
    const int*   ei     = (const int*)d_in[1];
    const float* W1     = (const float*)d_in[2];
    const float* a_src1 = (const float*)d_in[3];
    const float* a_dst1 = (const float*)d_in[4];
    const float* b1     = (const float*)d_in[5];
    const float* W2     = (const float*)d_in[6];
    const float* a_src2 = (const float*)d_in[7];
    const float* a_dst2 = (const float*)d_in[8];
    const float* b2     = (const float*)d_in[9];
    const float* fc_w   = (const float*)d_in[10];
    const float* fc_b   = (const float*)d_in[11];
    float* out = (float*)d_out;

    const int* srcA = ei;
    const int* dstA = ei + N_EDGES;

    // workspace layout (pads after index buffers as OOB insurance)
    float* ws = (float*)d_ws;
    size_t off = 0;
    unsigned int* xb    = (unsigned int*)(ws + off); off += (size_t)N_NODES * 64;   // 12.8 MB
    int4* rec      = (int4*)(ws + off); off += (size_t)E_TOT * 4 + 256;             // 13.6 MB
    int* posE      = (int*)(ws + off); off += E_TOT + 256;                          //  3.4 MB
    float* as1     = ws + off; off += (size_t)N_NODES * HEADS;
    float* ad1     = ws + off; off += (size_t)N_NODES * HEADS;
    float2* az     = (float2*)(ws + off); off += (size_t)N_NODES * 2;
    float* ad2     = ws + off; off += N_NODES;
    float* p_src   = ws + off; off += IN_DIM * HEADS;
    float* p_dst   = ws + off; off += IN_DIM * HEADS;
    float* v_s     = ws + off; off += C1;
    float* v_d     = ws + off; off += C1;
    float* v_z     = ws + off; off += C1;
    float* cst     = ws + off; off += 2;
    unsigned int* W1b = (unsigned int*)(ws + off); off += 16384;     // 64 KB packed bf16
    int* rowptr    = (int*)(ws + off); off += N_NODES + 1 + 256;     // +pad
    int* bsum      = (int*)(ws + off); off += 256;
    int* boff      = (int*)(ws + off); off += 256;
    int* deg       = (int*)(ws + off); off += N_NODES;
    hipMemsetAsync(deg, 0, N_NODES * sizeof(int), stream);

    // projection collapses + W1 bf16 B-fragment packing
    prep_kernel<<<1, 512, 0, stream>>>(W1, a_src1, a_dst1, W2, a_src2, a_dst2,
                                       b2, fc_w, fc_b, p_src, p_dst, v_s, v_d, v_z, cst, W1b);

    // fused: per-node proj + x->bf16 convert; count claims positions (posE)
    convproj_count_kernel<<<CP_BLOCKS + COUNT_BLOCKS, 256, 0, stream>>>(
        x, p_src, p_dst, dstA, as1, ad1, xb, deg, posE);

    // CSR: parallel scan + atomic-free fill (one 16 B sorted record per edge)
    blocksum_kernel<<<NB_SCAN, 256, 0, stream>>>(deg, bsum);
    scanbsum_kernel<<<1, 256, 0, stream>>>(bsum, boff);
    expand_kernel<<<NB_SCAN, 256, 0, stream>>>(deg, boff, rowptr);
    fillw3_kernel<<<COUNT_BLOCKS, 256, 0, stream>>>(srcA, dstA, rowptr, posE,
                                                    as1, ad1, rec);

    // FUSED layer-1 aggregation + MFMA MLP (8 waves/block, rec prefetch)
    agg1mlp_kernel<<<N_NODES / 16, 512, 0, stream>>>(rowptr, rec, xb, W1b, b1,
                                                     v_s, v_d, v_z, az, ad2);

    // layer 2 + final: scalar gather
    agg2z_kernel<<<(N_NODES * 8 + 255) / 256, 256, 0, stream>>>(rowptr, rec, az, ad2, cst, out);
}

// Round 4
// 247.105 us; speedup vs baseline: 1.0353x; 1.0353x over previous
//
#include <hip/hip_runtime.h>
#include <hip/hip_fp16.h>

#define N_NODES 50000
#define N_EDGES 800000
#define E_TOT   850000           // edges + self loops
#define IN_DIM  128
#define HID     64
#define HEADS   4
#define C1      256              // HEADS*HID
#define OUT_DIM 64
#define NEG_SLOPE 0.2f

#define CP_NODES   32                              // nodes per proj block
#define CP_BLOCKS  ((N_NODES + CP_NODES - 1) / CP_NODES)   // 1563
#define COUNT_BLOCKS ((E_TOT + 255) / 256)         // 3321
#define NB_SCAN ((N_NODES + 255) / 256)            // 196

typedef __attribute__((ext_vector_type(8))) short v8s;   // 8 bf16 (4 VGPRs)
typedef __attribute__((ext_vector_type(4))) float v4f;   // MFMA accumulator

// ---- bf16 helpers (manual: bf16 = top 16 bits of fp32, RNE) ----------------
__device__ __forceinline__ unsigned int bf16_rne(float f) {
    unsigned int u = __float_as_uint(f);
    return (u + 0x7FFFu + ((u >> 16) & 1u)) >> 16;
}
__device__ __forceinline__ unsigned int bf16_pack2(float a, float b) {
    return bf16_rne(a) | (bf16_rne(b) << 16);
}
__device__ __forceinline__ float bf16_lo(unsigned int u) { return __uint_as_float(u << 16); }
__device__ __forceinline__ float bf16_hi(unsigned int u) { return __uint_as_float(u & 0xFFFF0000u); }

// ---- fp16 pack helpers for edge weights ------------------------------------
__device__ __forceinline__ unsigned int f16_pack2(float a, float b) {
    __half2 h = __floats2half2_rn(a, b);
    return *(unsigned int*)&h;
}
__device__ __forceinline__ float2 f16_unp2(unsigned int u) {
    __half2 h = *(__half2*)&u;
    return __half22float2(h);
}

// ---------------------------------------------------------------------------
// prep (v2, WIDE): block 0 = projection collapses; blocks 1..32 = W1 bf16
// B-fragment packing (512 uints each). Was 1 block on 1 CU (~serial).
// ---------------------------------------------------------------------------
__global__ __launch_bounds__(512) void prep_kernel(
    const float* __restrict__ W1, const float* __restrict__ a_src1,
    const float* __restrict__ a_dst1,
    const float* __restrict__ W2, const float* __restrict__ a_src2,
    const float* __restrict__ a_dst2, const float* __restrict__ b2,
    const float* __restrict__ fc_w, const float* __restrict__ fc_b,
    float* __restrict__ p_src, float* __restrict__ p_dst,
    float* __restrict__ v_s, float* __restrict__ v_d, float* __restrict__ v_z,
    float* __restrict__ cst, unsigned int* __restrict__ W1b)
{
    const int t = threadIdx.x;
    if (blockIdx.x > 0) {
        // W1 -> bf16 B-fragment packing (16384 uints total, 512 per block)
        int idx = (blockIdx.x - 1) * 512 + t;
        int i    = idx & 3;
        int lane = (idx >> 2) & 63;
        int kk   = (idx >> 8) & 3;
        int nt   = (idx >> 10) & 3;
        int hh   = idx >> 12;
        int k0 = kk * 32 + (lane >> 4) * 8 + i * 2;
        int c  = hh * 64 + nt * 16 + (lane & 15);
        W1b[idx] = bf16_pack2(W1[(size_t)k0 * C1 + c], W1[(size_t)(k0 + 1) * C1 + c]);
        return;
    }
    // ---- block 0: collapse vectors ----
    const int k = t >> 2, h = t & 3;          // 512 = 128 k * 4 h
    const float* wrow = W1 + k * C1 + h * HID;
    const float* as = a_src1 + h * HID;
    const float* ad = a_dst1 + h * HID;
    float s = 0.f, d = 0.f;
    for (int c = 0; c < HID; c++) {
        float w = wrow[c];
        s = fmaf(w, as[c], s);
        d = fmaf(w, ad[c], d);
    }
    p_src[k * HEADS + h] = s;
    p_dst[k * HEADS + h] = d;

    if (t < C1) {                              // layer-2 collapse vectors
        const float* w2row = W2 + t * OUT_DIM;
        float vs = 0.f, vd = 0.f, vz = 0.f;
        for (int c = 0; c < OUT_DIM; c++) {
            float w = w2row[c];
            vs = fmaf(w, a_src2[c], vs);
            vd = fmaf(w, a_dst2[c], vd);
            vz = fmaf(w, fc_w[c], vz);
        }
        v_s[t] = vs; v_d[t] = vd; v_z[t] = vz;
    }
    if (t == 0) {
        float s2 = 0.f;
        for (int c = 0; c < OUT_DIM; c++) s2 = fmaf(b2[c], fc_w[c], s2);
        cst[0] = s2 + fc_b[0];
    }
}

// ---------------------------------------------------------------------------
// convproj_count: fused launch (round-17 proven mapping). Unchanged.
// ---------------------------------------------------------------------------
__global__ __launch_bounds__(256) void convproj_count_kernel(
    const float* __restrict__ x, const float* __restrict__ p_src,
    const float* __restrict__ p_dst, const int* __restrict__ dst_a,
    float* __restrict__ as1, float* __restrict__ ad1,
    unsigned int* __restrict__ xb, int* __restrict__ deg,
    int* __restrict__ posE)
{
    if (blockIdx.x >= CP_BLOCKS) {             // ---- count part ----
        int j = (blockIdx.x - CP_BLOCKS) * 256 + threadIdx.x;
        if (j < E_TOT) {
            int d = (j < N_EDGES) ? dst_a[j] : (j - N_EDGES);   // self loop
            posE[j] = atomicAdd(&deg[d], 1);
        }
        return;
    }
    // ---- proj + convert part ----
    __shared__ float ps[IN_DIM * HEADS];       // 2 KB
    __shared__ float pd[IN_DIM * HEADS];       // 2 KB
    const int t = threadIdx.x;
    for (int i = t; i < IN_DIM * HEADS; i += 256) { ps[i] = p_src[i]; pd[i] = p_dst[i]; }
    __syncthreads();
    const int wv   = t >> 6;
    const int lane = t & 63;
    float4 p0 = *(const float4*)(ps + (lane * 2) * HEADS);
    float4 p1 = *(const float4*)(ps + (lane * 2 + 1) * HEADS);
    float4 q0 = *(const float4*)(pd + (lane * 2) * HEADS);
    float4 q1 = *(const float4*)(pd + (lane * 2 + 1) * HEADS);
    const int nodeBase = blockIdx.x * CP_NODES + wv * 8;   // wave: 8 contiguous nodes
    #pragma unroll
    for (int i = 0; i < 8; i++) {
        const int node = nodeBase + i;
        if (node >= N_NODES) break;
        float2 xv = *(const float2*)(x + (size_t)node * IN_DIM + lane * 2);
        xb[(size_t)node * 64 + lane] = bf16_pack2(xv.x, xv.y);
        float s0 = xv.x * p0.x + xv.y * p1.x;
        float s1 = xv.x * p0.y + xv.y * p1.y;
        float s2 = xv.x * p0.z + xv.y * p1.z;
        float s3 = xv.x * p0.w + xv.y * p1.w;
        float d0 = xv.x * q0.x + xv.y * q1.x;
        float d1 = xv.x * q0.y + xv.y * q1.y;
        float d2 = xv.x * q0.z + xv.y * q1.z;
        float d3 = xv.x * q0.w + xv.y * q1.w;
        #pragma unroll
        for (int off = 32; off; off >>= 1) {
            s0 += __shfl_down(s0, off, 64); s1 += __shfl_down(s1, off, 64);
            s2 += __shfl_down(s2, off, 64); s3 += __shfl_down(s3, off, 64);
            d0 += __shfl_down(d0, off, 64); d1 += __shfl_down(d1, off, 64);
            d2 += __shfl_down(d2, off, 64); d3 += __shfl_down(d3, off, 64);
        }
        if (lane == 0) {
            float4 sv = {s0, s1, s2, s3};
            float4 dv = {d0, d1, d2, d3};
            *(float4*)(as1 + node * 4) = sv;
            *(float4*)(ad1 + node * 4) = dv;
        }
    }
}

// ---------------------------------------------------------------------------
// scanfuse: blocksum+scanbsum+expand in ONE kernel. 196 blocks (all
// co-resident on 256 CUs). Block totals published via device-scope atomics;
// block 0 scans the 196 totals and publishes per-block prefixes; all blocks
// spin on their prefix, then write rowptr. Values published as v+1 (0 =
// not ready). aggP/incP zeroed by the host-side memset each launch.
// ---------------------------------------------------------------------------
__global__ __launch_bounds__(256) void scanfuse_kernel(
    const int* __restrict__ deg, int* __restrict__ rowptr,
    int* aggP, int* incP)
{
    __shared__ int ps[256];
    __shared__ int bs[256];
    __shared__ int sprev;
    const int t = threadIdx.x;
    const int b = blockIdx.x;
    int i = b * 256 + t;
    int v = (i < N_NODES) ? deg[i] : 0;
    ps[t] = v;
    __syncthreads();
    for (int off = 1; off < 256; off <<= 1) {
        int u = (t >= off) ? ps[t - off] : 0;
        __syncthreads();
        ps[t] += u;
        __syncthreads();
    }
    if (t == 255) atomicExch(&aggP[b], ps[255] + 1);   // publish total (+1 flag)
    if (b == 0) {
        int val = 0;
        if (t < NB_SCAN) {
            while ((val = atomicAdd(&aggP[t], 0)) == 0) {}
            val -= 1;
        }
        bs[t] = (t < NB_SCAN) ? val : 0;
        __syncthreads();
        for (int off = 1; off < 256; off <<= 1) {
            int u = (t >= off) ? bs[t - off] : 0;
            __syncthreads();
            bs[t] += u;
            __syncthreads();
        }
        if (t < NB_SCAN) atomicExch(&incP[t], (bs[t] - val) + 1);  // exclusive
    }
    if (t == 0) {
        int val;
        while ((val = atomicAdd(&incP[b], 0)) == 0) {}
        sprev = val - 1;
    }
    __syncthreads();
    if (i <= N_NODES) rowptr[i] = sprev + ps[t] - v;   // exclusive node prefix
}

// ---------------------------------------------------------------------------
// fillw3: atomic-free CSR fill with ONE 16 B sorted record per edge:
// rec[slot] = {src, w01(2xf16), w23(2xf16), 0}. Unchanged.
// ---------------------------------------------------------------------------
__global__ void fillw3_kernel(const int* __restrict__ src_a, const int* __restrict__ dst_a,
                              const int* __restrict__ rowptr, const int* __restrict__ posE,
                              const float* __restrict__ as1, const float* __restrict__ ad1,
                              int4* __restrict__ rec)
{
    int j = blockIdx.x * blockDim.x + threadIdx.x;
    if (j >= E_TOT) return;
    int s, d;
    if (j < N_EDGES) { s = src_a[j]; d = dst_a[j]; }
    else             { s = j - N_EDGES; d = s; }
    int slot = rowptr[d] + posE[j];
    float4 A  = *(const float4*)(as1 + s * 4);
    float4 Dv = *(const float4*)(ad1 + d * 4);
    float a0 = A.x + Dv.x, a1 = A.y + Dv.y, a2 = A.z + Dv.z, a3 = A.w + Dv.w;
    a0 = a0 > 0.f ? a0 : NEG_SLOPE * a0;
    a1 = a1 > 0.f ? a1 : NEG_SLOPE * a1;
    a2 = a2 > 0.f ? a2 : NEG_SLOPE * a2;
    a3 = a3 > 0.f ? a3 : NEG_SLOPE * a3;
    int4 r;
    r.x = s;
    r.y = (int)f16_pack2(__expf(a0), __expf(a1));
    r.z = (int)f16_pack2(__expf(a2), __expf(a3));
    r.w = 0;
    rec[slot] = r;                             // single 16 B scatter
}

// ---------------------------------------------------------------------------
// agg1mlp (v3): 256 thr / 4 waves / 4 nodes-per-wave (proven 36-VGPR shape)
//  + rec software-prefetch pipeline. __launch_bounds__(256,6): VGPR cap 80
//  (no spill), 6 blocks/CU = 24 waves/CU; 12500 waves / 6144 resident =
//  2.03 occupancy rounds (near-zero tail).
// ---------------------------------------------------------------------------
__global__ __launch_bounds__(256, 6) void agg1mlp_kernel(
    const int* __restrict__ rowptr, const int4* __restrict__ rec,
    const unsigned int* __restrict__ xb,
    const unsigned int* __restrict__ W1b, const float* __restrict__ b1,
    const float* __restrict__ v_s, const float* __restrict__ v_d,
    const float* __restrict__ v_z,
    float2* __restrict__ az, float* __restrict__ ad2)
{
    __shared__ unsigned int xsh[16 * 260];     // 16.6 KB bf16 tile (+pad)
    __shared__ float pr[4 * 16 * 3];           // 768 B cross-wave partials
    const int t = threadIdx.x;
    const int nodeBase = blockIdx.x * 16;      // 3125 blocks * 16 = 50000 exact
    const int wv   = t >> 6;                   // 0..3
    const int lane = t & 63;

    // ---- Phase A: aggregate 4 nodes per wave, straight into LDS ----
    #pragma unroll 1
    for (int i = 0; i < 4; i++) {
        const int ln = wv * 4 + i;             // local node 0..15
        const int n  = nodeBase + ln;
        const int e0 = rowptr[n], e1 = rowptr[n + 1];

        float2 acc0 = {0,0}, acc1 = {0,0}, acc2 = {0,0}, acc3 = {0,0};
        float den0 = 0, den1 = 0, den2 = 0, den3 = 0;
        int e = e0;
        int4 R0, R1, R2, R3;
        if (e + 4 <= e1) {                     // pipeline prologue
            R0 = rec[e]; R1 = rec[e + 1]; R2 = rec[e + 2]; R3 = rec[e + 3];
        }
        while (e + 4 <= e1) {
            // gathers depending on current (already-arrived) records
            unsigned int xu0 = xb[(size_t)R0.x * 64 + lane];
            unsigned int xu1 = xb[(size_t)R1.x * 64 + lane];
            unsigned int xu2 = xb[(size_t)R2.x * 64 + lane];
            unsigned int xu3 = xb[(size_t)R3.x * 64 + lane];
            unsigned int wy0 = R0.y, wz0 = R0.z, wy1 = R1.y, wz1 = R1.z;
            unsigned int wy2 = R2.y, wz2 = R2.z, wy3 = R3.y, wz3 = R3.z;
            e += 4;
            if (e + 4 <= e1) {                 // prefetch NEXT records
                R0 = rec[e]; R1 = rec[e + 1]; R2 = rec[e + 2]; R3 = rec[e + 3];
            }
            float2 W0a = f16_unp2(wy0), W0b = f16_unp2(wz0);
            float2 W1a = f16_unp2(wy1), W1b_ = f16_unp2(wz1);
            float2 W2a = f16_unp2(wy2), W2b = f16_unp2(wz2);
            float2 W3a = f16_unp2(wy3), W3b = f16_unp2(wz3);
            float a0 = bf16_lo(xu0), b0 = bf16_hi(xu0);
            float a1 = bf16_lo(xu1), b1v = bf16_hi(xu1);
            float a2 = bf16_lo(xu2), b2v = bf16_hi(xu2);
            float a3 = bf16_lo(xu3), b3v = bf16_hi(xu3);
            acc0.x = fmaf(W0a.x, a0, acc0.x); acc0.y = fmaf(W0a.x, b0, acc0.y);
            acc1.x = fmaf(W0a.y, a0, acc1.x); acc1.y = fmaf(W0a.y, b0, acc1.y);
            acc2.x = fmaf(W0b.x, a0, acc2.x); acc2.y = fmaf(W0b.x, b0, acc2.y);
            acc3.x = fmaf(W0b.y, a0, acc3.x); acc3.y = fmaf(W0b.y, b0, acc3.y);
            acc0.x = fmaf(W1a.x, a1, acc0.x); acc0.y = fmaf(W1a.x, b1v, acc0.y);
            acc1.x = fmaf(W1a.y, a1, acc1.x); acc1.y = fmaf(W1a.y, b1v, acc1.y);
            acc2.x = fmaf(W1b_.x, a1, acc2.x); acc2.y = fmaf(W1b_.x, b1v, acc2.y);
            acc3.x = fmaf(W1b_.y, a1, acc3.x); acc3.y = fmaf(W1b_.y, b1v, acc3.y);
            acc0.x = fmaf(W2a.x, a2, acc0.x); acc0.y = fmaf(W2a.x, b2v, acc0.y);
            acc1.x = fmaf(W2a.y, a2, acc1.x); acc1.y = fmaf(W2a.y, b2v, acc1.y);
            acc2.x = fmaf(W2b.x, a2, acc2.x); acc2.y = fmaf(W2b.x, b2v, acc2.y);
            acc3.x = fmaf(W2b.y, a2, acc3.x); acc3.y = fmaf(W2b.y, b2v, acc3.y);
            acc0.x = fmaf(W3a.x, a3, acc0.x); acc0.y = fmaf(W3a.x, b3v, acc0.y);
            acc1.x = fmaf(W3a.y, a3, acc1.x); acc1.y = fmaf(W3a.y, b3v, acc1.y);
            acc2.x = fmaf(W3b.x, a3, acc2.x); acc2.y = fmaf(W3b.x, b3v, acc2.y);
            acc3.x = fmaf(W3b.y, a3, acc3.x); acc3.y = fmaf(W3b.y, b3v, acc3.y);
            den0 += (W0a.x + W1a.x) + (W2a.x + W3a.x);
            den1 += (W0a.y + W1a.y) + (W2a.y + W3a.y);
            den2 += (W0b.x + W1b_.x) + (W2b.x + W3b.x);
            den3 += (W0b.y + W1b_.y) + (W2b.y + W3b.y);
        }
        for (; e < e1; e++) {                  // 0..3 remainder edges
            int4 r0 = rec[e];
            unsigned int xu = xb[(size_t)r0.x * 64 + lane];
            float2 Wa = f16_unp2(r0.y), Wb = f16_unp2(r0.z);
            float xa = bf16_lo(xu), xbv = bf16_hi(xu);
            acc0.x = fmaf(Wa.x, xa, acc0.x); acc0.y = fmaf(Wa.x, xbv, acc0.y);
            acc1.x = fmaf(Wa.y, xa, acc1.x); acc1.y = fmaf(Wa.y, xbv, acc1.y);
            acc2.x = fmaf(Wb.x, xa, acc2.x); acc2.y = fmaf(Wb.x, xbv, acc2.y);
            acc3.x = fmaf(Wb.y, xa, acc3.x); acc3.y = fmaf(Wb.y, xbv, acc3.y);
            den0 += Wa.x; den1 += Wa.y; den2 += Wb.x; den3 += Wb.y;
        }
        float i0 = 1.f / (den0 + 1e-16f), i1 = 1.f / (den1 + 1e-16f);
        float i2 = 1.f / (den2 + 1e-16f), i3 = 1.f / (den3 + 1e-16f);
        unsigned int* o = xsh + ln * 260 + lane;   // c = h*64 + lane
        o[0 * 64] = bf16_pack2(acc0.x * i0, acc0.y * i0);
        o[1 * 64] = bf16_pack2(acc1.x * i1, acc1.y * i1);
        o[2 * 64] = bf16_pack2(acc2.x * i2, acc2.y * i2);
        o[3 * 64] = bf16_pack2(acc3.x * i3, acc3.y * i3);
    }
    __syncthreads();

    {   // ---- Phase B: MFMA + register epilogue; wave = head ----
        const int h = wv;
        const int m = lane & 15, quad = lane >> 4;
        const unsigned int* abase = xsh + m * 260 + h * 64 + quad * 4;
        v8s af0 = *(const v8s*)(abase + 0);
        v8s af1 = *(const v8s*)(abase + 16);
        v8s af2 = *(const v8s*)(abase + 32);
        v8s af3 = *(const v8s*)(abase + 48);

        float Sr[4] = {0,0,0,0}, Dr[4] = {0,0,0,0}, Zr[4] = {0,0,0,0};
        #pragma unroll
        for (int nt = 0; nt < 4; nt++) {
            const unsigned int* bbase = W1b + (size_t)(h * 16 + nt * 4) * 256 + lane * 4;
            v4f acc = {0.f, 0.f, 0.f, 0.f};
            acc = __builtin_amdgcn_mfma_f32_16x16x32_bf16(af0, *(const v8s*)(bbase + 0 * 256), acc, 0, 0, 0);
            acc = __builtin_amdgcn_mfma_f32_16x16x32_bf16(af1, *(const v8s*)(bbase + 1 * 256), acc, 0, 0, 0);
            acc = __builtin_amdgcn_mfma_f32_16x16x32_bf16(af2, *(const v8s*)(bbase + 2 * 256), acc, 0, 0, 0);
            acc = __builtin_amdgcn_mfma_f32_16x16x32_bf16(af3, *(const v8s*)(bbase + 3 * 256), acc, 0, 0, 0);
            const int c = h * 64 + nt * 16 + m;
            float bb = b1[c], vsc = v_s[c], vdc = v_d[c], vzc = v_z[c];
            #pragma unroll
            for (int r = 0; r < 4; r++) {
                float o = acc[r] + bb;
                o = o > 0.f ? o : __expf(o) - 1.f;     // ELU
                Sr[r] = fmaf(o, vsc, Sr[r]);
                Dr[r] = fmaf(o, vdc, Dr[r]);
                Zr[r] = fmaf(o, vzc, Zr[r]);
            }
        }
        #pragma unroll
        for (int off = 8; off; off >>= 1) {            // reduce over 16 cols
            #pragma unroll
            for (int r = 0; r < 4; r++) {
                Sr[r] += __shfl_down(Sr[r], off, 16);
                Dr[r] += __shfl_down(Dr[r], off, 16);
                Zr[r] += __shfl_down(Zr[r], off, 16);
            }
        }
        if (m == 0) {
            #pragma unroll
            for (int r = 0; r < 4; r++) {
                const int row = quad * 4 + r;          // local node 0..15
                pr[(h * 16 + row) * 3 + 0] = Sr[r];
                pr[(h * 16 + row) * 3 + 1] = Dr[r];
                pr[(h * 16 + row) * 3 + 2] = Zr[r];
            }
        }
    }
    __syncthreads();

    if (t < 16) {   // ---- cross-head reduce + store ----
        float s = 0.f, d = 0.f, z = 0.f;
        #pragma unroll
        for (int w = 0; w < 4; w++) {
            s += pr[(w * 16 + t) * 3 + 0];
            d += pr[(w * 16 + t) * 3 + 1];
            z += pr[(w * 16 + t) * 3 + 2];
        }
        const int node = nodeBase + t;
        float2 azv = {s, z};
        az[node]  = azv;
        ad2[node] = d;
    }
}

// ---------------------------------------------------------------------------
// agg2z: out[n] = sum_e w_e * z[src] / sum_e w_e + cst.  Reads rec[e].x.
// ---------------------------------------------------------------------------
__global__ __launch_bounds__(256) void agg2z_kernel(
    const int* __restrict__ rowptr, const int4* __restrict__ rec,
    const float2* __restrict__ az, const float* __restrict__ ad2,
    const float* __restrict__ cst, float* __restrict__ out)
{
    int gid  = blockIdx.x * blockDim.x + threadIdx.x;
    int n    = gid >> 3;                       // 8 lanes per node
    int sl   = threadIdx.x & 7;
    if (n >= N_NODES) return;
    const float adh = ad2[n];
    const int e0 = rowptr[n], e1 = rowptr[n + 1];

    float acc = 0.f, den = 0.f;
    for (int e = e0 + sl; e < e1; e += 8) {
        int s = rec[e].x;
        float2 v = az[s];
        float a = v.x + adh;
        a = a > 0.f ? a : NEG_SLOPE * a;
        float w = __expf(a);
        acc = fmaf(w, v.y, acc);
        den += w;
    }
    #pragma unroll
    for (int off = 4; off; off >>= 1) {
        acc += __shfl_down(acc, off, 8);
        den += __shfl_down(den, off, 8);
    }
    if (sl == 0) out[n] = acc / (den + 1e-16f) + cst[0];
}

extern "C" void kernel_launch(void* const* d_in, const int* in_sizes, int n_in,
                              void* d_out, int out_size, void* d_ws, size_t ws_size,
                              hipStream_t stream)
{
    const float* x      = (const float*)d_in[0];
    const int*   ei     = (const int*)d_in[1];
    const float* W1     = (const float*)d_in[2];
    const float* a_src1 = (const float*)d_in[3];
    const float* a_dst1 = (const float*)d_in[4];
    const float* b1     = (const float*)d_in[5];
    const float* W2     = (const float*)d_in[6];
    const float* a_src2 = (const float*)d_in[7];
    const float* a_dst2 = (const float*)d_in[8];
    const float* b2     = (const float*)d_in[9];
    const float* fc_w   = (const float*)d_in[10];
    const float* fc_b   = (const float*)d_in[11];
    float* out = (float*)d_out;

    const int* srcA = ei;
    const int* dstA = ei + N_EDGES;

    // workspace layout (pads after index buffers as OOB insurance)
    float* ws = (float*)d_ws;
    size_t off = 0;
    unsigned int* xb    = (unsigned int*)(ws + off); off += (size_t)N_NODES * 64;   // 12.8 MB
    int4* rec      = (int4*)(ws + off); off += (size_t)E_TOT * 4 + 256;             // 13.6 MB
    int* posE      = (int*)(ws + off); off += E_TOT + 256;                          //  3.4 MB
    float* as1     = ws + off; off += (size_t)N_NODES * HEADS;
    float* ad1     = ws + off; off += (size_t)N_NODES * HEADS;
    float2* az     = (float2*)(ws + off); off += (size_t)N_NODES * 2;
    float* ad2     = ws + off; off += N_NODES;
    float* p_src   = ws + off; off += IN_DIM * HEADS;
    float* p_dst   = ws + off; off += IN_DIM * HEADS;
    float* v_s     = ws + off; off += C1;
    float* v_d     = ws + off; off += C1;
    float* v_z     = ws + off; off += C1;
    float* cst     = ws + off; off += 2;
    unsigned int* W1b = (unsigned int*)(ws + off); off += 16384;     // 64 KB packed bf16
    int* rowptr    = (int*)(ws + off); off += N_NODES + 1 + 256;     // +pad
    int* aggP      = (int*)(ws + off); off += 256;                   // scan publish
    int* incP      = (int*)(ws + off); off += 256;                   // scan publish
    int* deg       = (int*)(ws + off); off += N_NODES;
    // one memset covers aggP + incP + deg (contiguous)
    hipMemsetAsync(aggP, 0, (512 + N_NODES) * sizeof(int), stream);

    // projection collapses + W1 bf16 B-fragment packing (wide: 33 blocks)
    prep_kernel<<<33, 512, 0, stream>>>(W1, a_src1, a_dst1, W2, a_src2, a_dst2,
                                        b2, fc_w, fc_b, p_src, p_dst, v_s, v_d, v_z, cst, W1b);

    // fused: per-node proj + x->bf16 convert; count claims positions (posE)
    convproj_count_kernel<<<CP_BLOCKS + COUNT_BLOCKS, 256, 0, stream>>>(
        x, p_src, p_dst, dstA, as1, ad1, xb, deg, posE);

    // CSR scan: single fused kernel (publish/spin, all 196 blocks co-resident)
    scanfuse_kernel<<<NB_SCAN, 256, 0, stream>>>(deg, rowptr, aggP, incP);

    // atomic-free fill (one 16 B sorted record per edge)
    fillw3_kernel<<<COUNT_BLOCKS, 256, 0, stream>>>(srcA, dstA, rowptr, posE,
                                                    as1, ad1, rec);

    // FUSED layer-1 aggregation + MFMA MLP (4 waves, rec prefetch, no spills)
    agg1mlp_kernel<<<N_NODES / 16, 256, 0, stream>>>(rowptr, rec, xb, W1b, b1,
                                                     v_s, v_d, v_z, az, ad2);

    // layer 2 + final: scalar gather
    agg2z_kernel<<<(N_NODES * 8 + 255) / 256, 256, 0, stream>>>(rowptr, rec, az, ad2, cst, out);
}